// Round 1
// baseline (319.995 us; speedup 1.0000x reference)
//
#include <hip/hip_runtime.h>
#include <math.h>

// Problem constants (fixed by the reference's setup_inputs):
//   x: (32, 512, 2049) fp32 ; outputs: (32, 512, 1024) fp32
//   segments: n_lin (~631) linear, n_cub (~104) cubic, n_tri (~289) triangular-max
#define NI 2049          // inputs per row
#define MAXW 64          // max packed triangular window width (actual max ~28)

// ---------------------------------------------------------------------------
// Preprocess: for each triangular output row, find the finite-weight window in
// the dense (n_tri x NI) weights and pack it. Runs every launch (ws is
// re-poisoned by the harness); cost is trivial (289 blocks x 2049 scan).
// ---------------------------------------------------------------------------
__global__ void logscale_preproc(const float* __restrict__ w, int n_in,
                                 int* __restrict__ tri_start,
                                 int* __restrict__ tri_cnt,
                                 float* __restrict__ wpack) {
    const int i = blockIdx.x;
    __shared__ int smin, smax;
    if (threadIdx.x == 0) { smin = n_in; smax = -1; }
    __syncthreads();

    int lmin = n_in, lmax = -1;
    const float* wr = w + (size_t)i * n_in;
    for (int b = threadIdx.x; b < n_in; b += blockDim.x) {
        float v = wr[b];
        if (v > -1e30f) {               // finite weights are >= ~-12 dB
            lmin = min(lmin, b);
            lmax = max(lmax, b);
        }
    }
    atomicMin(&smin, lmin);
    atomicMax(&smax, lmax);
    __syncthreads();

    int s = smin;
    int cnt = smax - smin + 1;
    if (cnt > MAXW) cnt = MAXW;         // safety clamp (never hit for this cfg)
    if (cnt < 1) { s = 0; cnt = 1; }    // defensive (row always has a 0.0 entry)
    if (threadIdx.x == 0) { tri_start[i] = s; tri_cnt[i] = cnt; }
    for (int j = threadIdx.x; j < MAXW; j += blockDim.x) {
        wpack[(size_t)i * MAXW + j] = (j < cnt) ? wr[s + j] : -INFINITY;
    }
}

// ---------------------------------------------------------------------------
// Main kernel: one block per row. Row staged in LDS; each thread computes
// strided outputs across the three segments.
// ---------------------------------------------------------------------------
__global__ __launch_bounds__(256) void logscale_main(
    const float* __restrict__ x,
    const float* __restrict__ flin,
    const float* __restrict__ fcub,
    const int*   __restrict__ pidx,
    const int*   __restrict__ tri_start,
    const int*   __restrict__ tri_cnt,
    const float* __restrict__ wpack,
    float* __restrict__ out,
    int n_lin, int n_cub, int n_tri) {

    const int row = blockIdx.x;
    __shared__ float lds[NI];

    const float* xr = x + (size_t)row * NI;
    for (int b = threadIdx.x; b < NI; b += blockDim.x) lds[b] = xr[b];
    __syncthreads();

    const int n_out = n_lin + n_cub + n_tri;
    float* orow = out + (size_t)row * n_out;

    for (int o = threadIdx.x; o < n_out; o += blockDim.x) {
        float r;
        if (o < n_lin) {
            // linear interp: x0 + f*(x1-x0)
            const int i0 = pidx[o];
            const int i1 = pidx[n_lin + o];
            const float f = flin[o];
            const float x0 = lds[i0];
            const float x1 = lds[i1];
            r = x0 + f * (x1 - x0);
        } else if (o < n_lin + n_cub) {
            // Catmull-Rom-style cubic
            const int i = o - n_lin;
            const float c = fcub[i];
            const int i0 = (int)floorf(c);
            const float f = c - (float)i0;
            const float xm1 = lds[i0 - 1];
            const float x0  = lds[i0];
            const float x1  = lds[i0 + 1];
            const float x2  = lds[i0 + 2];
            r = x0 + 0.5f * f * (x1 - xm1 +
                    f * (2.0f * xm1 - 5.0f * x0 + 4.0f * x1 - x2 +
                    f * (3.0f * (x0 - x1) + x2 - xm1)));
        } else {
            // triangular window max
            const int i = o - n_lin - n_cub;
            const int s = tri_start[i];
            const int cnt = tri_cnt[i];
            const float* wp = wpack + (size_t)i * MAXW;
            float m = -INFINITY;
            for (int j = 0; j < cnt; ++j) {
                m = fmaxf(m, lds[s + j] + wp[j]);
            }
            r = m;
        }
        orow[o] = r;
    }
}

extern "C" void kernel_launch(void* const* d_in, const int* in_sizes, int n_in,
                              void* d_out, int out_size, void* d_ws, size_t ws_size,
                              hipStream_t stream) {
    (void)n_in; (void)ws_size;
    const float* x     = (const float*)d_in[0];
    const float* flin  = (const float*)d_in[1];
    const float* fcub  = (const float*)d_in[2];
    const float* w     = (const float*)d_in[3];
    const int*   pidx  = (const int*)d_in[4];
    float* out = (float*)d_out;

    const int n_lin  = in_sizes[1];
    const int n_cub  = in_sizes[2];
    const int n_tri  = in_sizes[3] / NI;
    const int n_rows = in_sizes[0] / NI;
    (void)out_size;

    // Workspace layout: tri_start[n_tri] | tri_cnt[n_tri] | wpack[n_tri*MAXW]
    int*   tri_start = (int*)d_ws;
    int*   tri_cnt   = tri_start + n_tri;
    float* wpack     = (float*)(tri_cnt + n_tri);

    if (n_tri > 0) {
        logscale_preproc<<<n_tri, 256, 0, stream>>>(w, NI, tri_start, tri_cnt, wpack);
    }
    logscale_main<<<n_rows, 256, 0, stream>>>(x, flin, fcub, pidx,
                                              tri_start, tri_cnt, wpack,
                                              out, n_lin, n_cub, n_tri);
}